// Round 6
// baseline (168.909 us; speedup 1.0000x reference)
//
#include <hip/hip_runtime.h>
#include <hip/hip_bf16.h>

// GAT layer: B=2, N=2048, C_IN=128, H=16, c=8.
// e(i,j) = exp(lrelu(lp_i+lc_j)) = max(exp(lp)exp(lc), exp(.2lp)exp(.2lc)),
// unshifted (|logits| << 88). Round 6 = round 5 with the cvt_pkrtz return-type
// fixed (bit_cast __fp16x2 -> _Float16x2): j-paired inner loop, v_dot2_f32_f16
// full-rate dot2s, h packed as f16 j-pairs in proj, __launch_bounds__(512,4).
// d_out = [out: B*N*128][adj copy: B*N*N]

#define B_   2
#define N_   2048
#define CIN_ 128
#define H_   16
#define C_   8

typedef float v2f __attribute__((ext_vector_type(2)));
typedef _Float16 h2 __attribute__((ext_vector_type(2)));

__device__ inline h2 pk_f16(float a, float b) {
#if __has_builtin(__builtin_amdgcn_cvt_pkrtz)
  return __builtin_bit_cast(h2, __builtin_amdgcn_cvt_pkrtz(a, b));
#else
  h2 r; r.x = (_Float16)a; r.y = (_Float16)b; return r;
#endif
}

__device__ inline float dot2(h2 a, h2 b, float c) {
#if __has_builtin(__builtin_amdgcn_fdot2)
  return __builtin_amdgcn_fdot2(a, b, c, false);
#else
  return c + (float)a.x * (float)b.x + (float)a.y * (float)b.y;
#endif
}

__device__ inline h2 as_h2(unsigned int u) { return __builtin_bit_cast(h2, u); }

__global__ __launch_bounds__(128) void proj_kernel(
    const float* __restrict__ nf, const float* __restrict__ W,
    const float* __restrict__ bias, const float* __restrict__ a,
    unsigned int* __restrict__ hP, float* __restrict__ lpT,
    float* __restrict__ lcT) {
  const int row0 = blockIdx.x * 2;       // 2 consecutive rows (same batch; N even)
  const int t    = threadIdx.x;          // output column 0..127
  __shared__ float sNf[2][CIN_];
  if (t < 64) {
    ((float4*)&sNf[0][0])[t] = ((const float4*)(nf + (long)row0 * CIN_))[t];
  }
  __syncthreads();
  float acc0 = bias[t], acc1 = acc0;
#pragma unroll 16
  for (int k = 0; k < CIN_; ++k) {
    const float w = W[k * 128 + t];
    acc0 = fmaf(sNf[0][k], w, acc0);
    acc1 = fmaf(sNf[1][k], w, acc1);
  }
  const int h = t >> 3, kc = t & 7;
  const int b = row0 >> 11, n0 = row0 & (N_ - 1);
  // packed f16 j-pair: low = even row (j0), high = odd row (j1)
  hP[((long)(b * H_ + h) * (N_ / 2) + (n0 >> 1)) * C_ + kc] =
      __builtin_bit_cast(unsigned int, pk_f16(acc0, acc1));
  const float ap = a[h * 16 + kc], ac = a[h * 16 + 8 + kc];
  float accr[2] = {acc0, acc1};
#pragma unroll
  for (int r = 0; r < 2; ++r) {
    float lpv = accr[r] * ap, lcv = accr[r] * ac;
#pragma unroll
    for (int s = 1; s < 8; s <<= 1) {
      lpv += __shfl_xor(lpv, s);
      lcv += __shfl_xor(lcv, s);
    }
    if (kc == 0) {
      lpT[(long)(b * H_ + h) * N_ + n0 + r] = lpv;
      lcT[(long)(b * H_ + h) * N_ + n0 + r] = lcv;
    }
  }
}

__global__ __launch_bounds__(512, 4) void attn_kernel(
    const float* __restrict__ adj, const unsigned int* __restrict__ hP,
    const float* __restrict__ lpT, const float* __restrict__ lcT,
    float* __restrict__ out, float* __restrict__ adj_out) {
  const int hgroup = blockIdx.x & 1;     // which 8 heads
  const int tile   = blockIdx.x >> 1;
  const int b      = tile >> 8;          // 256 i-tiles per batch
  const int i0     = (tile & 255) * 8;
  const int tid    = threadIdx.x;
  const int wid    = tid >> 6;           // 0..7
  const int lane   = tid & 63;

  __shared__ float sAdj[8][N_];          // 64 KB

  // Stage adjacency rows (float4) + fused adj copy to d_out (hgroup 0 only).
  {
    const float4* arow = (const float4*)(adj + ((long)(b * N_ + i0 + wid)) * N_);
    float4* orow = (float4*)(adj_out + ((long)(b * N_ + i0 + wid)) * N_);
    float4* lrow4 = (float4*)(&sAdj[wid][0]);
#pragma unroll
    for (int ch = 0; ch < 8; ++ch) {
      const int idx = ch * 64 + lane;
      const float4 v = arow[idx];
      lrow4[idx] = v;
      if (hgroup == 0) orow[idx] = v;
    }
  }
  __syncthreads();

  const int  hw   = hgroup * 8 + wid;    // this wave's head
  const long base = (long)(b * H_ + hw) * N_;
  const float2* lc2 = (const float2*)(lcT + base);          // j-pairs
  const uint4*  hp4 = (const uint4*)(hP + (base / 2) * C_); // 2 uint4 per pair

  float P1[8], P2[8], lsum[8], acc[8][8];
#pragma unroll
  for (int r = 0; r < 8; ++r) {
    const float lp = lpT[base + i0 + r];
    P1[r] = __expf(lp);
    P2[r] = __expf(0.2f * lp);
    lsum[r] = 0.0f;
#pragma unroll
    for (int k = 0; k < 8; ++k) acc[r][k] = 0.0f;
  }

  // 16 iterations; lane owns j-pair jp = jj*64+lane (j = 2jp, 2jp+1).
  for (int jj = 0; jj < 16; ++jj) {
    const int jp = jj * 64 + lane;
    const uint4  ha = hp4[jp * 2];       // f16 pairs, feats 0..3
    const uint4  hb = hp4[jp * 2 + 1];   // feats 4..7
    const float2 lc = lc2[jp];

    const v2f Q1 = (v2f){__expf(lc.x), __expf(lc.y)};
    const v2f Q2 = (v2f){__expf(0.2f * lc.x), __expf(0.2f * lc.y)};

#pragma unroll
    for (int r = 0; r < 8; ++r) {
      const float2 av = *(const float2*)(&sAdj[r][jp * 2]);
      v2f e2 = __builtin_elementwise_max(Q1 * P1[r], Q2 * P2[r]);
      e2 *= (v2f){av.x, av.y};
      lsum[r] += e2.x + e2.y;
      const h2 eh = pk_f16(e2.x, e2.y);
      acc[r][0] = dot2(eh, as_h2(ha.x), acc[r][0]);
      acc[r][1] = dot2(eh, as_h2(ha.y), acc[r][1]);
      acc[r][2] = dot2(eh, as_h2(ha.z), acc[r][2]);
      acc[r][3] = dot2(eh, as_h2(ha.w), acc[r][3]);
      acc[r][4] = dot2(eh, as_h2(hb.x), acc[r][4]);
      acc[r][5] = dot2(eh, as_h2(hb.y), acc[r][5]);
      acc[r][6] = dot2(eh, as_h2(hb.z), acc[r][6]);
      acc[r][7] = dot2(eh, as_h2(hb.w), acc[r][7]);
    }
  }

  // Full 64-lane butterfly reduction.
#pragma unroll
  for (int s = 1; s < 64; s <<= 1) {
#pragma unroll
    for (int r = 0; r < 8; ++r) {
      lsum[r] += __shfl_xor(lsum[r], s);
#pragma unroll
      for (int k = 0; k < 8; ++k) acc[r][k] += __shfl_xor(acc[r][k], s);
    }
  }

  // lane -> (row rsel, feature ksel); all 64 lanes write one output each.
  const int rsel = lane >> 3, ksel = lane & 7;
  float av = 0.0f, lv = 1.0f;
#pragma unroll
  for (int r = 0; r < 8; ++r) {
    if (rsel == r) lv = lsum[r];
#pragma unroll
    for (int k = 0; k < 8; ++k)
      if (rsel == r && ksel == k) av = acc[r][k];
  }
  out[((long)(b * N_ + i0 + rsel)) * (H_ * C_) + hw * C_ + ksel] = av / lv;
}

extern "C" void kernel_launch(void* const* d_in, const int* in_sizes, int n_in,
                              void* d_out, int out_size, void* d_ws, size_t ws_size,
                              hipStream_t stream) {
  const float* nf   = (const float*)d_in[0];
  const float* adj  = (const float*)d_in[1];
  const float* W    = (const float*)d_in[2];
  const float* bias = (const float*)d_in[3];
  const float* a    = (const float*)d_in[4];

  float* out     = (float*)d_out;
  float* adj_out = out + (long)B_ * N_ * H_ * C_;   // 524288 offset

  unsigned int* hP = (unsigned int*)d_ws;           // B*H*(N/2)*C = 262144 dwords
  float* lpT = (float*)d_ws + 262144;               // B*H*N = 65536
  float* lcT = (float*)d_ws + 327680;               // B*H*N = 65536

  hipLaunchKernelGGL(proj_kernel, dim3(B_ * N_ / 2), dim3(128), 0, stream,
                     nf, W, bias, a, hP, lpT, lcT);
  hipLaunchKernelGGL(attn_kernel, dim3(B_ * (N_ / 8) * 2), dim3(512), 0, stream,
                     adj, hP, lpT, lcT, out, adj_out);
}

// Round 7
// 167.857 us; speedup vs baseline: 1.0063x; 1.0063x over previous
//
#include <hip/hip_runtime.h>
#include <hip/hip_bf16.h>

// GAT layer: B=2, N=2048, C_IN=128, H=16, c=8.
// e(i,j) = exp(lrelu(lp_i+lc_j)) = max(exp(lp)exp(lc), exp(.2lp)exp(.2lc)),
// unshifted (|logits| <= ~10 << 88; e <= ~3e3 fits f16).
// Round 7: no launch_bounds force (r6 spilled: WRITE 43MB), 1-deep global
// prefetch restored, Q=exp(lc)/exp(.2lc) precomputed in proj, sAdj packed f16
// (32KB LDS), mask via v_pk_mul_f16, lsum as dot2 against (1,1).
// d_out = [out: B*N*128][adj copy: B*N*N]

#define B_   2
#define N_   2048
#define CIN_ 128
#define H_   16
#define C_   8

typedef float v2f __attribute__((ext_vector_type(2)));
typedef _Float16 h2 __attribute__((ext_vector_type(2)));

__device__ inline h2 pk_f16(float a, float b) {
#if __has_builtin(__builtin_amdgcn_cvt_pkrtz)
  return __builtin_bit_cast(h2, __builtin_amdgcn_cvt_pkrtz(a, b));
#else
  h2 r; r.x = (_Float16)a; r.y = (_Float16)b; return r;
#endif
}

__device__ inline float dot2(h2 a, h2 b, float c) {
#if __has_builtin(__builtin_amdgcn_fdot2)
  return __builtin_amdgcn_fdot2(a, b, c, false);
#else
  return c + (float)a.x * (float)b.x + (float)a.y * (float)b.y;
#endif
}

__device__ inline h2 as_h2(unsigned int u) { return __builtin_bit_cast(h2, u); }
__device__ inline unsigned int as_u32(h2 v) { return __builtin_bit_cast(unsigned int, v); }

__global__ __launch_bounds__(128) void proj_kernel(
    const float* __restrict__ nf, const float* __restrict__ W,
    const float* __restrict__ bias, const float* __restrict__ a,
    unsigned int* __restrict__ hP, float* __restrict__ lpT,
    float* __restrict__ lq1, float* __restrict__ lq2) {
  const int row0 = blockIdx.x * 2;       // 2 consecutive rows (same batch; N even)
  const int t    = threadIdx.x;          // output column 0..127
  __shared__ float sNf[2][CIN_];
  if (t < 64) {
    ((float4*)&sNf[0][0])[t] = ((const float4*)(nf + (long)row0 * CIN_))[t];
  }
  __syncthreads();
  float acc0 = bias[t], acc1 = acc0;
#pragma unroll 16
  for (int k = 0; k < CIN_; ++k) {
    const float w = W[k * 128 + t];
    acc0 = fmaf(sNf[0][k], w, acc0);
    acc1 = fmaf(sNf[1][k], w, acc1);
  }
  const int h = t >> 3, kc = t & 7;
  const int b = row0 >> 11, n0 = row0 & (N_ - 1);
  // packed f16 j-pair: low = even row (j0), high = odd row (j1)
  hP[((long)(b * H_ + h) * (N_ / 2) + (n0 >> 1)) * C_ + kc] =
      as_u32(pk_f16(acc0, acc1));
  const float ap = a[h * 16 + kc], ac = a[h * 16 + 8 + kc];
  float accr[2] = {acc0, acc1};
#pragma unroll
  for (int r = 0; r < 2; ++r) {
    float lpv = accr[r] * ap, lcv = accr[r] * ac;
#pragma unroll
    for (int s = 1; s < 8; s <<= 1) {
      lpv += __shfl_xor(lpv, s);
      lcv += __shfl_xor(lcv, s);
    }
    if (kc == 0) {
      const long o = (long)(b * H_ + h) * N_ + n0 + r;
      lpT[o] = lpv;
      lq1[o] = __expf(lcv);
      lq2[o] = __expf(0.2f * lcv);
    }
  }
}

__global__ __launch_bounds__(512) void attn_kernel(
    const float* __restrict__ adj, const unsigned int* __restrict__ hP,
    const float* __restrict__ lpT, const float* __restrict__ lq1,
    const float* __restrict__ lq2, float* __restrict__ out,
    float* __restrict__ adj_out) {
  const int hgroup = blockIdx.x & 1;     // which 8 heads
  const int tile   = blockIdx.x >> 1;
  const int b      = tile >> 8;          // 256 i-tiles per batch
  const int i0     = (tile & 255) * 8;
  const int tid    = threadIdx.x;
  const int wid    = tid >> 6;           // 0..7
  const int lane   = tid & 63;

  __shared__ unsigned int sAdjH[8][N_ / 2];   // 32 KB: f16 j-pairs per row

  // Stage adjacency rows as packed-f16 pairs + fused adj copy (hgroup 0 only).
  {
    const float4* arow = (const float4*)(adj + ((long)(b * N_ + i0 + wid)) * N_);
    float4* orow = (float4*)(adj_out + ((long)(b * N_ + i0 + wid)) * N_);
    uint2* srow = (uint2*)(&sAdjH[wid][0]);
#pragma unroll
    for (int ch = 0; ch < 8; ++ch) {
      const int idx = ch * 64 + lane;    // float4 index 0..511 (= uint2 index)
      const float4 v = arow[idx];
      srow[idx] = (uint2){as_u32(pk_f16(v.x, v.y)), as_u32(pk_f16(v.z, v.w))};
      if (hgroup == 0) orow[idx] = v;
    }
  }
  __syncthreads();

  const int  hw   = hgroup * 8 + wid;    // this wave's head
  const long base = (long)(b * H_ + hw) * N_;
  const float2* q1p = (const float2*)(lq1 + base);          // j-pairs
  const float2* q2p = (const float2*)(lq2 + base);
  const uint4*  hp4 = (const uint4*)(hP + (base / 2) * C_); // 2 uint4 per pair

  float P1[8], P2[8], lsum[8], acc[8][8];
#pragma unroll
  for (int r = 0; r < 8; ++r) {
    const float lp = lpT[base + i0 + r];
    P1[r] = __expf(lp);
    P2[r] = __expf(0.2f * lp);
    lsum[r] = 0.0f;
#pragma unroll
    for (int k = 0; k < 8; ++k) acc[r][k] = 0.0f;
  }

  const h2 ones = pk_f16(1.0f, 1.0f);

  // 16 iterations; lane owns j-pair jp = jj*64+lane; 1-deep global prefetch.
  uint4  ha_c = hp4[lane * 2];
  uint4  hb_c = hp4[lane * 2 + 1];
  float2 q1_c = q1p[lane];
  float2 q2_c = q2p[lane];
  for (int jj = 0; jj < 16; ++jj) {
    const int jpn = ((jj + 1) & 15) * 64 + lane;  // next (wraps harmlessly)
    const uint4  ha_n = hp4[jpn * 2];
    const uint4  hb_n = hp4[jpn * 2 + 1];
    const float2 q1_n = q1p[jpn];
    const float2 q2_n = q2p[jpn];
    const int jp = jj * 64 + lane;

    const v2f Q1 = (v2f){q1_c.x, q1_c.y};
    const v2f Q2 = (v2f){q2_c.x, q2_c.y};

#pragma unroll
    for (int r = 0; r < 8; ++r) {
      const v2f e2 = __builtin_elementwise_max(Q1 * P1[r], Q2 * P2[r]);
      const h2 ehm = pk_f16(e2.x, e2.y) * as_h2(sAdjH[r][jp]);
      lsum[r]   = dot2(ehm, ones, lsum[r]);
      acc[r][0] = dot2(ehm, as_h2(ha_c.x), acc[r][0]);
      acc[r][1] = dot2(ehm, as_h2(ha_c.y), acc[r][1]);
      acc[r][2] = dot2(ehm, as_h2(ha_c.z), acc[r][2]);
      acc[r][3] = dot2(ehm, as_h2(ha_c.w), acc[r][3]);
      acc[r][4] = dot2(ehm, as_h2(hb_c.x), acc[r][4]);
      acc[r][5] = dot2(ehm, as_h2(hb_c.y), acc[r][5]);
      acc[r][6] = dot2(ehm, as_h2(hb_c.z), acc[r][6]);
      acc[r][7] = dot2(ehm, as_h2(hb_c.w), acc[r][7]);
    }
    ha_c = ha_n; hb_c = hb_n; q1_c = q1_n; q2_c = q2_n;
  }

  // Full 64-lane butterfly reduction.
#pragma unroll
  for (int s = 1; s < 64; s <<= 1) {
#pragma unroll
    for (int r = 0; r < 8; ++r) {
      lsum[r] += __shfl_xor(lsum[r], s);
#pragma unroll
      for (int k = 0; k < 8; ++k) acc[r][k] += __shfl_xor(acc[r][k], s);
    }
  }

  // lane -> (row rsel, feature ksel); all 64 lanes write one output each.
  const int rsel = lane >> 3, ksel = lane & 7;
  float av = 0.0f, lv = 1.0f;
#pragma unroll
  for (int r = 0; r < 8; ++r) {
    if (rsel == r) lv = lsum[r];
#pragma unroll
    for (int k = 0; k < 8; ++k)
      if (rsel == r && ksel == k) av = acc[r][k];
  }
  out[((long)(b * N_ + i0 + rsel)) * (H_ * C_) + hw * C_ + ksel] = av / lv;
}

extern "C" void kernel_launch(void* const* d_in, const int* in_sizes, int n_in,
                              void* d_out, int out_size, void* d_ws, size_t ws_size,
                              hipStream_t stream) {
  const float* nf   = (const float*)d_in[0];
  const float* adj  = (const float*)d_in[1];
  const float* W    = (const float*)d_in[2];
  const float* bias = (const float*)d_in[3];
  const float* a    = (const float*)d_in[4];

  float* out     = (float*)d_out;
  float* adj_out = out + (long)B_ * N_ * H_ * C_;   // 524288 offset

  unsigned int* hP = (unsigned int*)d_ws;           // B*H*(N/2)*C = 262144 dwords
  float* lpT = (float*)d_ws + 262144;               // B*H*N = 65536
  float* lq1 = (float*)d_ws + 327680;               // B*H*N = 65536
  float* lq2 = (float*)d_ws + 393216;               // B*H*N = 65536

  hipLaunchKernelGGL(proj_kernel, dim3(B_ * N_ / 2), dim3(128), 0, stream,
                     nf, W, bias, a, hP, lpT, lq1, lq2);
  hipLaunchKernelGGL(attn_kernel, dim3(B_ * (N_ / 8) * 2), dim3(512), 0, stream,
                     adj, hP, lpT, lq1, lq2, out, adj_out);
}

// Round 8
// 158.202 us; speedup vs baseline: 1.0677x; 1.0610x over previous
//
#include <hip/hip_runtime.h>
#include <hip/hip_bf16.h>

// GAT layer: B=2, N=2048, C_IN=128, H=16, c=8.
// E(i,j) = exp(lrelu(lp_i+lc_j))*2^-12 = max(P1_i*Q1_j, P2_i*Q2_j)*adj, where
// P1=exp(lp)/64, Q1=exp(lc)/64, P2=exp(.2lp)/64, Q2=exp(.2lc)/64 (f16-safe:
// max logit ~11 empirically -> products <= ~16; scale cancels in softmax).
// Round 8: aggregation moved to MFMA f32_16x16x32_f16. A = E-tile [16i x 32j],
// B = [h feats 0..7 | ones | zeros] (feat-major hQ from proj) -> D gives both
// out-tile and lsum (ones column). No butterfly; E-production is 4 pk-f16
// ops per 8 values/lane. d_out = [out: B*N*128][adj copy: B*N*N]

#define B_   2
#define N_   2048
#define CIN_ 128
#define H_   16

typedef _Float16 h2  __attribute__((ext_vector_type(2)));
typedef _Float16 v8h __attribute__((ext_vector_type(8)));
typedef float    v4f __attribute__((ext_vector_type(4)));

#define SC6 0.015625f   // 2^-6

__device__ inline h2 pk_f16(float a, float b) {
  return __builtin_bit_cast(h2, __builtin_amdgcn_cvt_pkrtz(a, b));
}
__device__ inline unsigned as_u32(h2 v) { return __builtin_bit_cast(unsigned, v); }
__device__ inline h2 as_h2(unsigned u) { return __builtin_bit_cast(h2, u); }

__global__ __launch_bounds__(128) void proj_kernel(
    const float* __restrict__ nf, const float* __restrict__ W,
    const float* __restrict__ bias, const float* __restrict__ a,
    unsigned* __restrict__ hQ, unsigned* __restrict__ lq1,
    unsigned* __restrict__ lq2, float* __restrict__ lpT) {
  const int row0 = blockIdx.x * 2;       // 2 consecutive rows (same batch)
  const int t    = threadIdx.x;          // output column 0..127
  __shared__ float sNf[2][CIN_];
  if (t < 64) {
    ((float4*)&sNf[0][0])[t] = ((const float4*)(nf + (long)row0 * CIN_))[t];
  }
  __syncthreads();
  float acc0 = bias[t], acc1 = acc0;
#pragma unroll 16
  for (int k = 0; k < CIN_; ++k) {
    const float w = W[k * 128 + t];
    acc0 = fmaf(sNf[0][k], w, acc0);
    acc1 = fmaf(sNf[1][k], w, acc1);
  }
  const int h = t >> 3, kc = t & 7;
  const int b = row0 >> 11, n0 = row0 & (N_ - 1);
  const int bh = b * H_ + h;
  const int cdw = n0 >> 1;               // j-pair dword index
  // hQ: feat-major f16 [bh][feat 0..15][j]; feats 8..15 = ones/zeros filler
  hQ[(bh * 16 + kc) * (N_ / 2) + cdw] = as_u32(pk_f16(acc0, acc1));
#pragma unroll
  for (int i2 = 0; i2 < 2; ++i2) {       // fill feats 8..15 for all 32 bh
    const int u = t * 2 + i2;
    const int bh2 = u >> 3, f = 8 + (u & 7);
    hQ[(bh2 * 16 + f) * (N_ / 2) + cdw] = (f == 8) ? 0x3C003C00u : 0u;
  }
  const float ap = a[h * 16 + kc], ac = a[h * 16 + 8 + kc];
  float accr[2] = {acc0, acc1};
  float q1v[2], q2v[2], lpv2[2];
#pragma unroll
  for (int r = 0; r < 2; ++r) {
    float lpv = accr[r] * ap, lcv = accr[r] * ac;
#pragma unroll
    for (int s = 1; s < 8; s <<= 1) {
      lpv += __shfl_xor(lpv, s);
      lcv += __shfl_xor(lcv, s);
    }
    lpv2[r] = lpv;
    q1v[r] = __expf(lcv) * SC6;
    q2v[r] = __expf(0.2f * lcv) * SC6;
  }
  if (kc == 0) {
    lpT[bh * N_ + n0]     = lpv2[0];
    lpT[bh * N_ + n0 + 1] = lpv2[1];
    lq1[bh * (N_ / 2) + cdw] = as_u32(pk_f16(q1v[0], q1v[1]));
    lq2[bh * (N_ / 2) + cdw] = as_u32(pk_f16(q2v[0], q2v[1]));
  }
}

__global__ __launch_bounds__(512) void attn_kernel(
    const float* __restrict__ adj, const unsigned* __restrict__ hQ,
    const unsigned* __restrict__ lq1, const unsigned* __restrict__ lq2,
    const float* __restrict__ lpT, float* __restrict__ out,
    float* __restrict__ adj_out) {
  const int hgroup = blockIdx.x & 1;
  const int rest   = blockIdx.x >> 1;
  const int b      = rest >> 7;          // 128 i-tiles per batch
  const int i0     = (rest & 127) * 16;
  const int tid    = threadIdx.x;
  const int w      = tid >> 6;           // 0..7 (wave = head)
  const int lane   = tid & 63;

  __shared__ unsigned short sAdj[16][2056];   // f16 adjacency, +8 pad (banks)

  // Stage 16 adjacency rows (f32 -> f16) + fused adj copy (hgroup 0 only).
  {
    const float4* asrc = (const float4*)(adj + ((long)(b * N_ + i0)) * N_);
    float4* adst = (float4*)(adj_out + ((long)(b * N_ + i0)) * N_);
#pragma unroll
    for (int it = 0; it < 16; ++it) {
      const int g = it * 512 + tid;      // float4 index over 16x2048
      const int r = g >> 9, c4 = g & 511;
      const float4 v = asrc[g];
      *(uint2*)(&sAdj[r][c4 * 4]) =
          (uint2){as_u32(pk_f16(v.x, v.y)), as_u32(pk_f16(v.z, v.w))};
      if (hgroup == 0) adst[g] = v;
    }
  }
  __syncthreads();

  const int hw = hgroup * 8 + w;
  const int bh = b * H_ + hw;
  const int m  = lane & 15;              // A row / B col / D col
  const int q  = lane >> 4;              // k-quad

  const float lp = lpT[bh * N_ + i0 + m];
  const float p1 = __expf(lp) * SC6, p2 = __expf(0.2f * lp) * SC6;
  const h2 P1 = pk_f16(p1, p1), P2 = pk_f16(p2, p2);

  const unsigned* q1p = lq1 + bh * (N_ / 2);
  const unsigned* q2p = lq2 + bh * (N_ / 2);
  const unsigned* hp  = hQ + (bh * 16 + m) * (N_ / 2);

  v4f acc = {0.0f, 0.0f, 0.0f, 0.0f};

  uint4 Q1c = *(const uint4*)(q1p + q * 4);
  uint4 Q2c = *(const uint4*)(q2p + q * 4);
  uint4 Hc  = *(const uint4*)(hp  + q * 4);
  for (int ch = 0; ch < 64; ++ch) {
    const int nidx = ((ch + 1) & 63) * 16 + q * 4;   // next chunk (wraps)
    const uint4 Q1n = *(const uint4*)(q1p + nidx);
    const uint4 Q2n = *(const uint4*)(q2p + nidx);
    const uint4 Hn  = *(const uint4*)(hp  + nidx);

    const int jb = ch * 32 + q * 8;      // this lane's 8 j's
    const uint4 Av = *(const uint4*)(&sAdj[m][jb]);

    const h2 e0 = __builtin_elementwise_max(P1 * as_h2(Q1c.x), P2 * as_h2(Q2c.x)) * as_h2(Av.x);
    const h2 e1 = __builtin_elementwise_max(P1 * as_h2(Q1c.y), P2 * as_h2(Q2c.y)) * as_h2(Av.y);
    const h2 e2 = __builtin_elementwise_max(P1 * as_h2(Q1c.z), P2 * as_h2(Q2c.z)) * as_h2(Av.z);
    const h2 e3 = __builtin_elementwise_max(P1 * as_h2(Q1c.w), P2 * as_h2(Q2c.w)) * as_h2(Av.w);

    const v8h af = __builtin_bit_cast(v8h,
        (uint4){as_u32(e0), as_u32(e1), as_u32(e2), as_u32(e3)});
    const v8h bf = __builtin_bit_cast(v8h, Hc);
    acc = __builtin_amdgcn_mfma_f32_16x16x32_f16(af, bf, acc, 0, 0, 0);

    Q1c = Q1n; Q2c = Q2n; Hc = Hn;
  }

  // D: col = lane&15, row = q*4 + reg (m89-verified). lsum lives in col 8.
#pragma unroll
  for (int r = 0; r < 4; ++r) {
    const float lsum = __shfl(acc[r], q * 16 + 8);
    if (m < 8) {
      out[((long)(b * N_ + i0 + q * 4 + r)) * 128 + hw * 8 + m] = acc[r] / lsum;
    }
  }
}

extern "C" void kernel_launch(void* const* d_in, const int* in_sizes, int n_in,
                              void* d_out, int out_size, void* d_ws, size_t ws_size,
                              hipStream_t stream) {
  const float* nf   = (const float*)d_in[0];
  const float* adj  = (const float*)d_in[1];
  const float* W    = (const float*)d_in[2];
  const float* bias = (const float*)d_in[3];
  const float* a    = (const float*)d_in[4];

  float* out     = (float*)d_out;
  float* adj_out = out + (long)B_ * N_ * H_ * 8;    // 524288 offset

  unsigned* ws  = (unsigned*)d_ws;
  unsigned* hQ  = ws;                    // 32 bh * 16 feats * 1024 dw = 524288
  unsigned* lq1 = ws + 524288;           // 32 bh * 1024 dw = 32768
  unsigned* lq2 = ws + 557056;           // 32768
  float*    lpT = (float*)(ws + 589824); // 65536 floats

  hipLaunchKernelGGL(proj_kernel, dim3(B_ * N_ / 2), dim3(128), 0, stream,
                     nf, W, bias, a, hQ, lq1, lq2, lpT);
  hipLaunchKernelGGL(attn_kernel, dim3(B_ * (N_ / 16) * 2), dim3(512), 0, stream,
                     adj, hQ, lq1, lq2, lpT, out, adj_out);
}